// Round 2
// baseline (291.455 us; speedup 1.0000x reference)
//
#include <hip/hip_runtime.h>
#include <float.h>

#define NROWS 65536
#define DK 256
#define NCODES 1024
#define FLAG_CAP 8192
#define MARGIN1 0.15f   // f16 single-pass: sigma_d ~0.0065 -> 23 sigma + granule 0.0156
#define D_BIAS 384.0f   // d = enorm + 384 - 2acc in (394, 894): 8-bit pack granule <= 2^-6
#define TIE_EPS 2.0e-3f // fp32 rescan: sigma ~4e-5 -> 50 sigma; ties -> exact fp64 path

#define LOSS_OFF 16777216
#define IDX_OFF  16777217

// LDS fragment chunk stride (dist_fused): 64 fragments x 16 B = 1024 B payload,
// padded to 1040 B so stage-A wave-wide ds_write_b64 rotates 4 banks per chunk.
#define CHUNK_STRIDE 1040

// ---------------- ws layout (bytes) ----------------
#define WS_FLAG1   0        // int
#define WS_LOSSP   8        // double[64]
#define WS_ENORMD  520      // double[1024]
#define WS_ENORMF  8712     // float[1024]
#define WS_FROWS   12808    // int[FLAG_CAP] -> ends 45576
#define WS_IDX     45576    // int[65536]    -> ends 307720
#define WS_EHI     307728   // fp16[1024*256] frag-swizzled (512 KB)

typedef _Float16 f16x8 __attribute__((ext_vector_type(8)));
typedef float f32x4 __attribute__((ext_vector_type(4)));
typedef unsigned int uint32;

__device__ __forceinline__ uint32 packh2(float a, float b) {
  return (uint32)__builtin_bit_cast(unsigned short, (_Float16)a) |
         ((uint32)__builtin_bit_cast(unsigned short, (_Float16)b) << 16);
}

// ---- init: counters, fp64 E norms, E -> f16 fragment-swizzled Ehi ----
__global__ __launch_bounds__(256) void init_kernel(
    const float* __restrict__ E, double* __restrict__ enorm_d,
    float* __restrict__ enorm_f, uint4* __restrict__ Ehi,
    int* __restrict__ flag1, double* __restrict__ loss_part) {
  const int t = threadIdx.x;
  const int c = blockIdx.x * 8 + (t >> 5);
  const int g = t & 31;  // 8-element group within the code row
  if (blockIdx.x == 0) {
    if (t == 0) *flag1 = 0;
    if (t < 64) loss_part[t] = 0.0;
  }
  const float4* er4 = (const float4*)(E + (size_t)c * DK);
  const float4 va = er4[g * 2];
  const float4 vb = er4[g * 2 + 1];
  double s = (double)va.x * va.x + (double)va.y * va.y + (double)va.z * va.z + (double)va.w * va.w
           + (double)vb.x * vb.x + (double)vb.y * vb.y + (double)vb.z * vb.z + (double)vb.w * vb.w;
  uint4 h;
  h.x = packh2(va.x, va.y);
  h.y = packh2(va.z, va.w);
  h.z = packh2(vb.x, vb.y);
  h.w = packh2(vb.z, vb.w);
  const int ctg = c >> 8, cga = (c >> 4) & 15, col = c & 15;
  const int kc = g >> 2, quad = g & 3;
  Ehi[((size_t)((ctg * 8 + kc) * 16 + cga)) * 64 + (size_t)(quad * 16 + col)] = h;
  #pragma unroll
  for (int m = 1; m < 32; m <<= 1) s += __shfl_xor(s, m, 64);
  if (g == 0) {
    enorm_d[c] = s;
    enorm_f[c] = (float)s;
  }
}

// ---- phase 1 (fused): f16 MFMA distances + top-2 argmin + gather/loss tail ----
__global__ __launch_bounds__(256, 4) void dist_fused(
    const float* __restrict__ X, const uint4* __restrict__ Ehi,
    const float* __restrict__ E, const float* __restrict__ enorm_f,
    int* __restrict__ idx_ws, int* __restrict__ flag1, int* __restrict__ flag_rows,
    float* __restrict__ out, double* __restrict__ loss_part) {
  __shared__ __attribute__((aligned(16))) char lds[33280];
  const int tid = threadIdx.x;
  const int lane = tid & 63;
  const int wid = tid >> 6;
  const int col = lane & 15;
  const int rowBase = blockIdx.x * 64;

  // stage A: 64 rows x 256 k, fp32 -> fp16 RNE, fragment order (rotated chunks)
  {
    const float4* X4 = (const float4*)X + (size_t)rowBase * 64;
    #pragma unroll
    for (int i = 0; i < 16; ++i) {
      const int f4 = i * 256 + tid;
      const int row = f4 >> 6;
      const int k0 = (f4 & 63) << 2;
      const float4 v = X4[f4];
      uint2 p;
      p.x = packh2(v.x, v.y);
      p.y = packh2(v.z, v.w);
      const int chunk = (row >> 4) * 8 + (k0 >> 5);
      const int off = chunk * CHUNK_STRIDE
                      + (((k0 >> 3) & 3) * 16 + (row & 15)) * 16
                      + ((k0 >> 2) & 1) * 8;
      *(uint2*)(lds + off) = p;
    }
  }
  __syncthreads();

  float rv1[16], rv2[16];  // packed top-2 per row; wave-local idx in low 8 bits
  #pragma unroll
  for (int i = 0; i < 16; ++i) { rv1[i] = FLT_MAX; rv2[i] = FLT_MAX; }

  for (int ctg = 0; ctg < 4; ++ctg) {
    f32x4 acc[4][4];
    #pragma unroll
    for (int rg = 0; rg < 4; ++rg)
      #pragma unroll
      for (int cg = 0; cg < 4; ++cg) acc[rg][cg] = (f32x4){0.f, 0.f, 0.f, 0.f};

    #pragma unroll 2
    for (int ks = 0; ks < 8; ++ks) {
      const size_t ub = ((size_t)((ctg * 8 + ks) * 16 + wid * 4)) * 64 + (size_t)lane;
      f16x8 a[4], bh[4];
      #pragma unroll
      for (int cg = 0; cg < 4; ++cg) bh[cg] = *(const f16x8*)&Ehi[ub + (size_t)cg * 64];
      #pragma unroll
      for (int rg = 0; rg < 4; ++rg)
        a[rg] = *(const f16x8*)(lds + (rg * 8 + ks) * CHUNK_STRIDE + lane * 16);
      #pragma unroll
      for (int rg = 0; rg < 4; ++rg)
        #pragma unroll
        for (int cg = 0; cg < 4; ++cg)
          acc[rg][cg] = __builtin_amdgcn_mfma_f32_16x16x32_f16(a[rg], bh[cg], acc[rg][cg], 0, 0, 0);
    }
    // epilogue: d = ||e||^2 + BIAS - 2 acc; pack wave-local idx (8 bits)
    #pragma unroll
    for (int cg = 0; cg < 4; ++cg) {
      const int code = ctg * 256 + wid * 64 + cg * 16 + col;
      const float en = enorm_f[code] + D_BIAS;
      const uint32 li = (uint32)((ctg << 6) | (cg << 4) | col);
      #pragma unroll
      for (int rg = 0; rg < 4; ++rg)
        #pragma unroll
        for (int reg = 0; reg < 4; ++reg) {
          const int i = rg * 4 + reg;
          const float d = fmaf(-2.0f, acc[rg][cg][reg], en);
          const float p = __builtin_bit_cast(float,
              (__builtin_bit_cast(uint32, d) & 0xFFFFFF00u) | li);
          rv2[i] = fminf(rv2[i], fmaxf(rv1[i], p));
          rv1[i] = fminf(rv1[i], p);
        }
    }
  }

  // merge 16 cols within each quad (packed => lowest local idx wins ties)
  #pragma unroll
  for (int i = 0; i < 16; ++i) {
    #pragma unroll
    for (int m = 1; m < 16; m <<= 1) {
      const float o1 = __shfl_xor(rv1[i], m, 64);
      const float o2 = __shfl_xor(rv2[i], m, 64);
      rv2[i] = fminf(fminf(rv2[i], o2), fmaxf(rv1[i], o1));
      rv1[i] = fminf(rv1[i], o1);
    }
  }

  __syncthreads();  // all waves done reading A region
  float* M = (float*)lds;          // [row 64][wave 4][2]  (2 KB)
  int* idxs = (int*)(lds + 4096);  // [64]
  if (col == 0) {
    const int quad = lane >> 4;
    #pragma unroll
    for (int i = 0; i < 16; ++i) {
      const int row = (i >> 2) * 16 + quad * 4 + (i & 3);
      M[(row * 4 + wid) * 2 + 0] = rv1[i];
      M[(row * 4 + wid) * 2 + 1] = rv2[i];
    }
  }
  __syncthreads();
  if (tid < 64) {
    const float a1 = M[(tid * 4 + 0) * 2], a2 = M[(tid * 4 + 0) * 2 + 1];
    const float b1 = M[(tid * 4 + 1) * 2], b2 = M[(tid * 4 + 1) * 2 + 1];
    const float c1 = M[(tid * 4 + 2) * 2], c2 = M[(tid * 4 + 2) * 2 + 1];
    const float d1 = M[(tid * 4 + 3) * 2], d2 = M[(tid * 4 + 3) * 2 + 1];
    const float lo1 = fminf(a1, b1), hi1 = fmaxf(a1, b1);
    const float lo2 = fminf(c1, d1), hi2 = fmaxf(c1, d1);
    const float r1 = fminf(lo1, lo2);
    const float s1 = fminf(fmaxf(lo1, lo2), fminf(hi1, hi2));
    const float r2 = fminf(fminf(fminf(a2, b2), fminf(c2, d2)), s1);
    const int w1 = (r1 == a1) ? 0 : (r1 == b1) ? 1 : (r1 == c1) ? 2 : 3;
    const uint32 u1 = __builtin_bit_cast(uint32, r1);
    const int li = (int)(u1 & 255u);
    const int code = ((li >> 6) & 3) * 256 + w1 * 64 + ((li >> 4) & 3) * 16 + (li & 15);
    const int row = rowBase + tid;
    idxs[tid] = code;
    idx_ws[row] = code;
    out[IDX_OFF + row] = (float)code;
    const float q1 = __builtin_bit_cast(float, u1 & 0xFFFFFF00u);
    const float q2 = __builtin_bit_cast(float, __builtin_bit_cast(uint32, r2) & 0xFFFFFF00u);
    if (q2 - q1 < MARGIN1) {
      const int p = atomicAdd(flag1, 1);
      if (p < FLAG_CAP) flag_rows[p] = row;
    }
  }
  __syncthreads();

  // fused tail: gather quantized, write, fp64 loss partial (provisional idx;
  // fixup64 rewrites flagged rows and adjusts the loss by the exact delta)
  const int rsub = tid >> 6, c4 = tid & 63;
  double ls = 0.0;
  #pragma unroll 4
  for (int i = 0; i < 16; ++i) {
    const int rl = i * 4 + rsub;
    const int row = rowBase + rl;
    const int idx = idxs[rl];
    const float4 q = ((const float4*)E)[(size_t)idx * 64 + c4];
    const float4 x = ((const float4*)X)[(size_t)row * 64 + c4];
    ((float4*)out)[(size_t)row * 64 + c4] = q;
    const double d0 = (double)q.x - (double)x.x;
    const double d1 = (double)q.y - (double)x.y;
    const double d2 = (double)q.z - (double)x.z;
    const double d3 = (double)q.w - (double)x.w;
    ls += d0 * d0 + d1 * d1 + d2 * d2 + d3 * d3;
  }
  #pragma unroll
  for (int o = 32; o > 0; o >>= 1) ls += __shfl_down(ls, o, 64);
  __shared__ double wsum[4];
  if ((tid & 63) == 0) wsum[tid >> 6] = ls;
  __syncthreads();
  if (tid == 0)
    atomicAdd(&loss_part[blockIdx.x & 63], wsum[0] + wsum[1] + wsum[2] + wsum[3]);
}

// ---- phase 2: re-resolution of flagged rows (4 rows/block) ----
// fp32 scan over all 1024 codes with LDS-staged, XOR-swizzled E chunks
// (coalesced global, conflict-free LDS both sides). Top-2 (value,index)
// tracked; if gap < TIE_EPS (rare, ~few rows grid-wide) fall back to the
// exact fp64 full rescan (divergent loads OK at that rarity). Changed rows:
// rewrite quantized output + idx, loss adjusted by direct fp64 recompute.
__global__ __launch_bounds__(256) void fixup64(
    const float* __restrict__ X, const float* __restrict__ E,
    const double* __restrict__ enorm_d, const float* __restrict__ enorm_f,
    const int* __restrict__ flag1, const int* __restrict__ flag_rows,
    const int* __restrict__ idx_ws, float* __restrict__ out,
    double* __restrict__ loss_part) {
  __shared__ __attribute__((aligned(16))) float xs[4][256];  // 4 KB
  __shared__ float4 es[2048];                                 // 32 KB, swizzled
  __shared__ double rv[256];
  __shared__ int ri[256];
  __shared__ float wv1[4][4], wv2[4][4];
  __shared__ int wi1[4][4];
  __shared__ float fin1[4], fin2[4];
  __shared__ int fini[4];
  __shared__ int rowsh[4], oldsh[4], newsh[4];

  int cnt = *flag1;
  if (cnt > FLAG_CAP) cnt = FLAG_CAP;
  const int fbase = blockIdx.x * 4;
  if (fbase >= cnt) return;
  const int nr = min(4, cnt - fbase);
  const int tid = threadIdx.x;
  if (tid < 4) {
    const int row = (tid < nr) ? flag_rows[fbase + tid] : flag_rows[fbase];
    rowsh[tid] = row;
    oldsh[tid] = idx_ws[row];
  }
  __syncthreads();
  for (int e = tid; e < 4 * 256; e += 256)
    xs[e >> 8][e & 255] = X[(size_t)rowsh[e >> 8] * DK + (e & 255)];
  __syncthreads();  // xs visible to all

  const float4* E4g = (const float4*)E;
  float acc[4][4];  // [cc][row]
  #pragma unroll
  for (int cc = 0; cc < 4; ++cc)
    #pragma unroll
    for (int r = 0; r < 4; ++r) acc[cc][r] = 0.f;

  const int f_st = tid & 7;   // float4 col for staging
  const int rr_st = tid >> 3; // 0..31 row group for staging
  const int sw = tid & 7;     // read-side swizzle

  for (int kb = 0; kb < 8; ++kb) {
    // xs dim-chunk into registers once per kb (broadcast LDS reads)
    float4 xr[4][8];
    #pragma unroll
    for (int r = 0; r < 4; ++r)
      #pragma unroll
      for (int f = 0; f < 8; ++f)
        xr[r][f] = ((const float4*)xs[r])[kb * 8 + f];
    #pragma unroll
    for (int cc = 0; cc < 4; ++cc) {
      __syncthreads();  // protect es overwrite
      #pragma unroll
      for (int p = 0; p < 8; ++p) {
        const int r = p * 32 + rr_st;
        es[r * 8 + (f_st ^ (r & 7))] = E4g[(size_t)(cc * 256 + r) * 64 + kb * 8 + f_st];
      }
      __syncthreads();
      #pragma unroll
      for (int f = 0; f < 8; ++f) {
        const float4 e4 = es[tid * 8 + (f ^ sw)];
        #pragma unroll
        for (int r = 0; r < 4; ++r)
          acc[cc][r] += e4.x * xr[r][f].x + e4.y * xr[r][f].y
                      + e4.z * xr[r][f].z + e4.w * xr[r][f].w;
      }
    }
  }

  // per-thread top-2 over its 4 codes (codes ascending -> '<' keeps lowest idx)
  float v1[4], v2[4];
  int i1[4];
  #pragma unroll
  for (int r = 0; r < 4; ++r) { v1[r] = FLT_MAX; v2[r] = FLT_MAX; i1[r] = 0; }
  #pragma unroll
  for (int cc = 0; cc < 4; ++cc) {
    const int code = cc * 256 + tid;
    const float en = enorm_f[code];
    #pragma unroll
    for (int r = 0; r < 4; ++r) {
      const float d = fmaf(-2.0f, acc[cc][r], en);
      if (d < v1[r]) { v2[r] = v1[r]; v1[r] = d; i1[r] = code; }
      else v2[r] = fminf(v2[r], d);
    }
  }

  // wave-level top-2 butterfly, then 4-wave merge
  const int lane = tid & 63, wid = tid >> 6;
  #pragma unroll
  for (int r = 0; r < 4; ++r) {
    float b1 = v1[r], b2 = v2[r];
    int bi = i1[r];
    #pragma unroll
    for (int m = 1; m < 64; m <<= 1) {
      const float o1 = __shfl_xor(b1, m, 64);
      const float o2 = __shfl_xor(b2, m, 64);
      const int oi = __shfl_xor(bi, m, 64);
      const float hi = fmaxf(b1, o1);
      b2 = fminf(fminf(b2, o2), hi);
      if (o1 < b1 || (o1 == b1 && oi < bi)) { b1 = o1; bi = oi; }
    }
    if (lane == 0) { wv1[wid][r] = b1; wi1[wid][r] = bi; wv2[wid][r] = b2; }
  }
  __syncthreads();
  if (tid < 4) {  // tid = row
    float b1 = wv1[0][tid], b2 = wv2[0][tid];
    int bi = wi1[0][tid];
    #pragma unroll
    for (int w = 1; w < 4; ++w) {
      const float o1 = wv1[w][tid], o2 = wv2[w][tid];
      const int oi = wi1[w][tid];
      b2 = fminf(fminf(b2, o2), fmaxf(b1, o1));
      if (o1 < b1 || (o1 == b1 && oi < bi)) { b1 = o1; bi = oi; }
    }
    fin1[tid] = b1;
    fin2[tid] = b2;
    fini[tid] = bi;
    newsh[tid] = bi;
  }
  __syncthreads();

  // rare exact-fp64 tie resolution (block-uniform branch per row)
  for (int r = 0; r < nr; ++r) {
    if (fin2[r] - fin1[r] < TIE_EPS) {
      double bd = 1e300;
      int bi_ = 0x7fffffff;
      for (int cc = 0; cc < 4; ++cc) {
        const int c = cc * 256 + tid;
        const float4* Er = (const float4*)(E + (size_t)c * DK);
        double s = 0.0;
        #pragma unroll 4
        for (int q = 0; q < 64; ++q) {
          const float4 ev = Er[q];
          const float4 xv = ((const float4*)xs[r])[q];
          s += (double)ev.x * xv.x + (double)ev.y * xv.y
             + (double)ev.z * xv.z + (double)ev.w * xv.w;
        }
        const double dd = enorm_d[c] - 2.0 * s;
        if (dd < bd) { bd = dd; bi_ = c; }  // c ascending per thread
      }
      rv[tid] = bd;
      ri[tid] = bi_;
      __syncthreads();
      for (int off = 128; off > 0; off >>= 1) {
        if (tid < off) {
          const double ov = rv[tid + off];
          const int oi = ri[tid + off];
          if (ov < rv[tid] || (ov == rv[tid] && oi < ri[tid])) {
            rv[tid] = ov;
            ri[tid] = oi;
          }
        }
        __syncthreads();
      }
      if (tid == 0) newsh[r] = ri[0];
      __syncthreads();
    }
  }

  // write-back changed rows + exact fp64 loss delta (direct recompute)
  for (int r = 0; r < nr; ++r) {
    const int newi = newsh[r];
    const int oldi = oldsh[r];
    if (newi != oldi) {
      const int row = rowsh[r];
      const float ev = E[(size_t)newi * DK + tid];
      const float eo = E[(size_t)oldi * DK + tid];
      const float x = xs[r][tid];
      out[(size_t)row * DK + tid] = ev;
      const double dn = (double)ev - (double)x;
      const double dl = (double)eo - (double)x;
      rv[tid] = dn * dn - dl * dl;
      __syncthreads();
      for (int off = 128; off > 0; off >>= 1) {
        if (tid < off) rv[tid] += rv[tid + off];
        __syncthreads();
      }
      if (tid == 0) {
        out[IDX_OFF + row] = (float)newi;
        atomicAdd(&loss_part[row & 63], rv[0]);
      }
      __syncthreads();
    }
  }
}

__global__ __launch_bounds__(64) void finalize(
    const double* __restrict__ loss_part, float* __restrict__ out) {
  double v = loss_part[threadIdx.x];
  for (int o = 32; o > 0; o >>= 1) v += __shfl_down(v, o, 64);
  if (threadIdx.x == 0) out[LOSS_OFF] = (float)(v / 16777216.0);
}

extern "C" void kernel_launch(void* const* d_in, const int* in_sizes, int n_in,
                              void* d_out, int out_size, void* d_ws, size_t ws_size,
                              hipStream_t stream) {
  const float* X = (const float*)d_in[0];  // [65536, 256]
  const float* E = (const float*)d_in[1];  // [1024, 256]
  float* out = (float*)d_out;
  char* ws = (char*)d_ws;

  int*    flag1     = (int*)(ws + WS_FLAG1);
  double* loss_part = (double*)(ws + WS_LOSSP);
  double* enorm_d   = (double*)(ws + WS_ENORMD);
  float*  enorm_f   = (float*)(ws + WS_ENORMF);
  int*    flag_rows = (int*)(ws + WS_FROWS);
  int*    idx_ws    = (int*)(ws + WS_IDX);
  uint4*  Ehi       = (uint4*)(ws + WS_EHI);

  hipLaunchKernelGGL(init_kernel, dim3(128), dim3(256), 0, stream,
                     E, enorm_d, enorm_f, Ehi, flag1, loss_part);
  hipLaunchKernelGGL(dist_fused, dim3(NROWS / 64), dim3(256), 0, stream,
                     X, Ehi, E, enorm_f, idx_ws, flag1, flag_rows, out, loss_part);
  hipLaunchKernelGGL(fixup64, dim3(FLAG_CAP / 4), dim3(256), 0, stream,
                     X, E, enorm_d, enorm_f, flag1, flag_rows, idx_ws, out, loss_part);
  hipLaunchKernelGGL(finalize, dim3(1), dim3(64), 0, stream, loss_part, out);
}

// Round 3
// 227.234 us; speedup vs baseline: 1.2826x; 1.2826x over previous
//
#include <hip/hip_runtime.h>
#include <float.h>

#define NROWS 65536
#define DK 256
#define NCODES 1024
#define FLAG_CAP 8192
#define MARGIN1 0.15f   // f16 single-pass: sigma_d ~0.0065 -> 23 sigma + granule 0.0156
#define D_BIAS 384.0f   // d = enorm + 384 - 2acc in (394, 894): 8-bit pack granule <= 2^-6
#define TIE_EPS 2.0e-3f // fp32 rescan: sigma ~4e-5 -> 50 sigma; ties -> exact fp64 path

#define LOSS_OFF 16777216
#define IDX_OFF  16777217

// LDS fragment chunk stride (dist_fused): 64 fragments x 16 B = 1024 B payload,
// padded to 1040 B so stage-A wave-wide ds_write_b64 rotates 4 banks per chunk.
#define CHUNK_STRIDE 1040

// ---------------- ws layout (bytes) ----------------
// (ENORMF bumped to 16B alignment for float4 loads in fixup_scan.)
#define WS_FLAG1   0        // int
#define WS_LOSSP   8        // double[64]
#define WS_ENORMD  520      // double[1024] -> ends 8712
#define WS_ENORMF  8720     // float[1024]  -> ends 12816 (16B aligned)
#define WS_FROWS   12816    // int[FLAG_CAP] -> ends 45584
#define WS_IDX     45584    // int[65536]    -> ends 307728
#define WS_EHI     307728   // fp16[1024*256] frag-swizzled (512 KB), dead after dist_fused
#define WS_ET      307728   // float[256][1024] E-transposed (1 MB) OVERLAYS Ehi:
                            // written by transposeE (after dist_fused), read by fixup_scan.
                            // ws high-water: 307728 + 1 MB = 1,356,304 B.

typedef _Float16 f16x8 __attribute__((ext_vector_type(8)));
typedef float f32x4 __attribute__((ext_vector_type(4)));
typedef unsigned int uint32;

__device__ __forceinline__ uint32 packh2(float a, float b) {
  return (uint32)__builtin_bit_cast(unsigned short, (_Float16)a) |
         ((uint32)__builtin_bit_cast(unsigned short, (_Float16)b) << 16);
}

// ---- init: counters, fp64 E norms, E -> f16 fragment-swizzled Ehi ----
__global__ __launch_bounds__(256) void init_kernel(
    const float* __restrict__ E, double* __restrict__ enorm_d,
    float* __restrict__ enorm_f, uint4* __restrict__ Ehi,
    int* __restrict__ flag1, double* __restrict__ loss_part) {
  const int t = threadIdx.x;
  const int c = blockIdx.x * 8 + (t >> 5);
  const int g = t & 31;  // 8-element group within the code row
  if (blockIdx.x == 0) {
    if (t == 0) *flag1 = 0;
    if (t < 64) loss_part[t] = 0.0;
  }
  const float4* er4 = (const float4*)(E + (size_t)c * DK);
  const float4 va = er4[g * 2];
  const float4 vb = er4[g * 2 + 1];
  double s = (double)va.x * va.x + (double)va.y * va.y + (double)va.z * va.z + (double)va.w * va.w
           + (double)vb.x * vb.x + (double)vb.y * vb.y + (double)vb.z * vb.z + (double)vb.w * vb.w;
  uint4 h;
  h.x = packh2(va.x, va.y);
  h.y = packh2(va.z, va.w);
  h.z = packh2(vb.x, vb.y);
  h.w = packh2(vb.z, vb.w);
  const int ctg = c >> 8, cga = (c >> 4) & 15, col = c & 15;
  const int kc = g >> 2, quad = g & 3;
  Ehi[((size_t)((ctg * 8 + kc) * 16 + cga)) * 64 + (size_t)(quad * 16 + col)] = h;
  #pragma unroll
  for (int m = 1; m < 32; m <<= 1) s += __shfl_xor(s, m, 64);
  if (g == 0) {
    enorm_d[c] = s;
    enorm_f[c] = (float)s;
  }
}

// ---- phase 1 (fused): f16 MFMA distances + top-2 argmin + gather/loss tail ----
__global__ __launch_bounds__(256, 4) void dist_fused(
    const float* __restrict__ X, const uint4* __restrict__ Ehi,
    const float* __restrict__ E, const float* __restrict__ enorm_f,
    int* __restrict__ idx_ws, int* __restrict__ flag1, int* __restrict__ flag_rows,
    float* __restrict__ out, double* __restrict__ loss_part) {
  __shared__ __attribute__((aligned(16))) char lds[33280];
  const int tid = threadIdx.x;
  const int lane = tid & 63;
  const int wid = tid >> 6;
  const int col = lane & 15;
  const int rowBase = blockIdx.x * 64;

  // stage A: 64 rows x 256 k, fp32 -> fp16 RNE, fragment order (rotated chunks)
  {
    const float4* X4 = (const float4*)X + (size_t)rowBase * 64;
    #pragma unroll
    for (int i = 0; i < 16; ++i) {
      const int f4 = i * 256 + tid;
      const int row = f4 >> 6;
      const int k0 = (f4 & 63) << 2;
      const float4 v = X4[f4];
      uint2 p;
      p.x = packh2(v.x, v.y);
      p.y = packh2(v.z, v.w);
      const int chunk = (row >> 4) * 8 + (k0 >> 5);
      const int off = chunk * CHUNK_STRIDE
                      + (((k0 >> 3) & 3) * 16 + (row & 15)) * 16
                      + ((k0 >> 2) & 1) * 8;
      *(uint2*)(lds + off) = p;
    }
  }
  __syncthreads();

  float rv1[16], rv2[16];  // packed top-2 per row; wave-local idx in low 8 bits
  #pragma unroll
  for (int i = 0; i < 16; ++i) { rv1[i] = FLT_MAX; rv2[i] = FLT_MAX; }

  for (int ctg = 0; ctg < 4; ++ctg) {
    f32x4 acc[4][4];
    #pragma unroll
    for (int rg = 0; rg < 4; ++rg)
      #pragma unroll
      for (int cg = 0; cg < 4; ++cg) acc[rg][cg] = (f32x4){0.f, 0.f, 0.f, 0.f};

    #pragma unroll 2
    for (int ks = 0; ks < 8; ++ks) {
      const size_t ub = ((size_t)((ctg * 8 + ks) * 16 + wid * 4)) * 64 + (size_t)lane;
      f16x8 a[4], bh[4];
      #pragma unroll
      for (int cg = 0; cg < 4; ++cg) bh[cg] = *(const f16x8*)&Ehi[ub + (size_t)cg * 64];
      #pragma unroll
      for (int rg = 0; rg < 4; ++rg)
        a[rg] = *(const f16x8*)(lds + (rg * 8 + ks) * CHUNK_STRIDE + lane * 16);
      #pragma unroll
      for (int rg = 0; rg < 4; ++rg)
        #pragma unroll
        for (int cg = 0; cg < 4; ++cg)
          acc[rg][cg] = __builtin_amdgcn_mfma_f32_16x16x32_f16(a[rg], bh[cg], acc[rg][cg], 0, 0, 0);
    }
    // epilogue: d = ||e||^2 + BIAS - 2 acc; pack wave-local idx (8 bits)
    #pragma unroll
    for (int cg = 0; cg < 4; ++cg) {
      const int code = ctg * 256 + wid * 64 + cg * 16 + col;
      const float en = enorm_f[code] + D_BIAS;
      const uint32 li = (uint32)((ctg << 6) | (cg << 4) | col);
      #pragma unroll
      for (int rg = 0; rg < 4; ++rg)
        #pragma unroll
        for (int reg = 0; reg < 4; ++reg) {
          const int i = rg * 4 + reg;
          const float d = fmaf(-2.0f, acc[rg][cg][reg], en);
          const float p = __builtin_bit_cast(float,
              (__builtin_bit_cast(uint32, d) & 0xFFFFFF00u) | li);
          rv2[i] = fminf(rv2[i], fmaxf(rv1[i], p));
          rv1[i] = fminf(rv1[i], p);
        }
    }
  }

  // merge 16 cols within each quad (packed => lowest local idx wins ties)
  #pragma unroll
  for (int i = 0; i < 16; ++i) {
    #pragma unroll
    for (int m = 1; m < 16; m <<= 1) {
      const float o1 = __shfl_xor(rv1[i], m, 64);
      const float o2 = __shfl_xor(rv2[i], m, 64);
      rv2[i] = fminf(fminf(rv2[i], o2), fmaxf(rv1[i], o1));
      rv1[i] = fminf(rv1[i], o1);
    }
  }

  __syncthreads();  // all waves done reading A region
  float* M = (float*)lds;          // [row 64][wave 4][2]  (2 KB)
  int* idxs = (int*)(lds + 4096);  // [64]
  if (col == 0) {
    const int quad = lane >> 4;
    #pragma unroll
    for (int i = 0; i < 16; ++i) {
      const int row = (i >> 2) * 16 + quad * 4 + (i & 3);
      M[(row * 4 + wid) * 2 + 0] = rv1[i];
      M[(row * 4 + wid) * 2 + 1] = rv2[i];
    }
  }
  __syncthreads();
  if (tid < 64) {
    const float a1 = M[(tid * 4 + 0) * 2], a2 = M[(tid * 4 + 0) * 2 + 1];
    const float b1 = M[(tid * 4 + 1) * 2], b2 = M[(tid * 4 + 1) * 2 + 1];
    const float c1 = M[(tid * 4 + 2) * 2], c2 = M[(tid * 4 + 2) * 2 + 1];
    const float d1 = M[(tid * 4 + 3) * 2], d2 = M[(tid * 4 + 3) * 2 + 1];
    const float lo1 = fminf(a1, b1), hi1 = fmaxf(a1, b1);
    const float lo2 = fminf(c1, d1), hi2 = fmaxf(c1, d1);
    const float r1 = fminf(lo1, lo2);
    const float s1 = fminf(fmaxf(lo1, lo2), fminf(hi1, hi2));
    const float r2 = fminf(fminf(fminf(a2, b2), fminf(c2, d2)), s1);
    const int w1 = (r1 == a1) ? 0 : (r1 == b1) ? 1 : (r1 == c1) ? 2 : 3;
    const uint32 u1 = __builtin_bit_cast(uint32, r1);
    const int li = (int)(u1 & 255u);
    const int code = ((li >> 6) & 3) * 256 + w1 * 64 + ((li >> 4) & 3) * 16 + (li & 15);
    const int row = rowBase + tid;
    idxs[tid] = code;
    idx_ws[row] = code;
    out[IDX_OFF + row] = (float)code;
    const float q1 = __builtin_bit_cast(float, u1 & 0xFFFFFF00u);
    const float q2 = __builtin_bit_cast(float, __builtin_bit_cast(uint32, r2) & 0xFFFFFF00u);
    if (q2 - q1 < MARGIN1) {
      const int p = atomicAdd(flag1, 1);
      if (p < FLAG_CAP) flag_rows[p] = row;
    }
  }
  __syncthreads();

  // fused tail: gather quantized, write, fp64 loss partial (provisional idx;
  // fixup rewrites flagged rows and adjusts the loss by the exact delta)
  const int rsub = tid >> 6, c4 = tid & 63;
  double ls = 0.0;
  #pragma unroll 4
  for (int i = 0; i < 16; ++i) {
    const int rl = i * 4 + rsub;
    const int row = rowBase + rl;
    const int idx = idxs[rl];
    const float4 q = ((const float4*)E)[(size_t)idx * 64 + c4];
    const float4 x = ((const float4*)X)[(size_t)row * 64 + c4];
    ((float4*)out)[(size_t)row * 64 + c4] = q;
    const double d0 = (double)q.x - (double)x.x;
    const double d1 = (double)q.y - (double)x.y;
    const double d2 = (double)q.z - (double)x.z;
    const double d3 = (double)q.w - (double)x.w;
    ls += d0 * d0 + d1 * d1 + d2 * d2 + d3 * d3;
  }
  #pragma unroll
  for (int o = 32; o > 0; o >>= 1) ls += __shfl_down(ls, o, 64);
  __shared__ double wsum[4];
  if ((tid & 63) == 0) wsum[tid >> 6] = ls;
  __syncthreads();
  if (tid == 0)
    atomicAdd(&loss_part[blockIdx.x & 63], wsum[0] + wsum[1] + wsum[2] + wsum[3]);
}

// ---- E transpose: Et[k][c] = E[c][k], 1 MB, runs after dist_fused ----
// 16 blocks x 256 thr: thread = (code c = b*64 + (t&63), k-quarter = t>>6).
// Reads: divergent 16B (L2-resident E). Writes: per-wave 64 consecutive c
// => 256 B fully coalesced column writes.
__global__ __launch_bounds__(256) void transposeE(
    const float* __restrict__ E, float* __restrict__ Et) {
  const int t = threadIdx.x;
  const int c = blockIdx.x * 64 + (t & 63);
  const int kq = t >> 6;  // 0..3
  const float4* E4 = (const float4*)(E + (size_t)c * DK) + kq * 16;
  #pragma unroll
  for (int q = 0; q < 16; ++q) {
    const float4 v = E4[q];
    const int k = kq * 64 + q * 4;
    Et[(size_t)k * NCODES + c] = v.x;
    Et[(size_t)(k + 1) * NCODES + c] = v.y;
    Et[(size_t)(k + 2) * NCODES + c] = v.z;
    Et[(size_t)(k + 3) * NCODES + c] = v.w;
  }
}

// ---- phase 2: re-resolution of flagged rows (4 rows/block) ----
// fp32 scan via Et: thread t owns codes 4t..4t+3; per k one fully-coalesced
// 1 KB wave load of Et row + one LDS broadcast of x (all 4 rows packed as
// float4). No barriers in the hot loop, no staging => short critical path
// (the R2 version serialized 64 barrier-phases per block: 158 us).
// Top-2 tracked; gap < TIE_EPS (rare) -> exact fp64 full rescan. Changed
// rows: rewrite quantized output + idx, loss adjusted by fp64 recompute.
__global__ __launch_bounds__(256) void fixup_scan(
    const float* __restrict__ X, const float* __restrict__ E,
    const float* __restrict__ Et, const double* __restrict__ enorm_d,
    const float* __restrict__ enorm_f, const int* __restrict__ flag1,
    const int* __restrict__ flag_rows, const int* __restrict__ idx_ws,
    float* __restrict__ out, double* __restrict__ loss_part) {
  __shared__ __attribute__((aligned(16))) float xsT[256][4];  // [k][row], 4 KB
  __shared__ double rv[256];
  __shared__ int ri[256];
  __shared__ float wv1[4][4], wv2[4][4];
  __shared__ int wi1[4][4];
  __shared__ float fin1[4], fin2[4];
  __shared__ int rowsh[4], oldsh[4], newsh[4];

  int cnt = *flag1;
  if (cnt > FLAG_CAP) cnt = FLAG_CAP;
  const int fbase = blockIdx.x * 4;
  if (fbase >= cnt) return;
  const int nr = min(4, cnt - fbase);
  const int tid = threadIdx.x;
  if (tid < 4) {
    const int row = (tid < nr) ? flag_rows[fbase + tid] : flag_rows[fbase];
    rowsh[tid] = row;
    oldsh[tid] = idx_ws[row];
  }
  __syncthreads();
  #pragma unroll
  for (int r = 0; r < 4; ++r)
    xsT[tid][r] = X[(size_t)rowsh[r] * DK + tid];
  __syncthreads();

  // main scan: 256 iters x {1 coalesced global f32x4 + 1 LDS b128 broadcast
  // + 16 FMA}, unroll 8 for load ILP (only ~1 block/CU -> need ILP not TLP).
  const f32x4* Et4 = (const f32x4*)Et;
  const f32x4* xv = (const f32x4*)xsT;
  f32x4 acc[4];
  #pragma unroll
  for (int r = 0; r < 4; ++r) acc[r] = (f32x4){0.f, 0.f, 0.f, 0.f};
  #pragma unroll 8
  for (int k = 0; k < 256; ++k) {
    const f32x4 e4 = Et4[(size_t)k * 256 + tid];
    const f32x4 xk = xv[k];
    acc[0] += e4 * xk[0];
    acc[1] += e4 * xk[1];
    acc[2] += e4 * xk[2];
    acc[3] += e4 * xk[3];
  }

  // per-thread top-2 over its 4 codes (j ascending -> lowest idx wins ties)
  float v1[4], v2[4];
  int i1[4];
  #pragma unroll
  for (int r = 0; r < 4; ++r) { v1[r] = FLT_MAX; v2[r] = FLT_MAX; i1[r] = 0; }
  const float4 en4 = ((const float4*)enorm_f)[tid];
  const float en[4] = {en4.x, en4.y, en4.z, en4.w};
  #pragma unroll
  for (int j = 0; j < 4; ++j) {
    const int code = tid * 4 + j;
    #pragma unroll
    for (int r = 0; r < 4; ++r) {
      const float d = fmaf(-2.0f, acc[r][j], en[j]);
      if (d < v1[r]) { v2[r] = v1[r]; v1[r] = d; i1[r] = code; }
      else v2[r] = fminf(v2[r], d);
    }
  }

  // wave-level top-2 butterfly, then 4-wave merge
  const int lane = tid & 63, wid = tid >> 6;
  #pragma unroll
  for (int r = 0; r < 4; ++r) {
    float b1 = v1[r], b2 = v2[r];
    int bi = i1[r];
    #pragma unroll
    for (int m = 1; m < 64; m <<= 1) {
      const float o1 = __shfl_xor(b1, m, 64);
      const float o2 = __shfl_xor(b2, m, 64);
      const int oi = __shfl_xor(bi, m, 64);
      const float hi = fmaxf(b1, o1);
      b2 = fminf(fminf(b2, o2), hi);
      if (o1 < b1 || (o1 == b1 && oi < bi)) { b1 = o1; bi = oi; }
    }
    if (lane == 0) { wv1[wid][r] = b1; wi1[wid][r] = bi; wv2[wid][r] = b2; }
  }
  __syncthreads();
  if (tid < 4) {  // tid = row
    float b1 = wv1[0][tid], b2 = wv2[0][tid];
    int bi = wi1[0][tid];
    #pragma unroll
    for (int w = 1; w < 4; ++w) {
      const float o1 = wv1[w][tid], o2 = wv2[w][tid];
      const int oi = wi1[w][tid];
      b2 = fminf(fminf(b2, o2), fmaxf(b1, o1));
      if (o1 < b1 || (o1 == b1 && oi < bi)) { b1 = o1; bi = oi; }
    }
    fin1[tid] = b1;
    fin2[tid] = b2;
    newsh[tid] = bi;
  }
  __syncthreads();

  // rare exact-fp64 tie resolution (block-uniform branch per row)
  for (int r = 0; r < nr; ++r) {
    if (fin2[r] - fin1[r] < TIE_EPS) {
      double bd = 1e300;
      int bi_ = 0x7fffffff;
      for (int cc = 0; cc < 4; ++cc) {
        const int c = cc * 256 + tid;
        const float4* Er = (const float4*)(E + (size_t)c * DK);
        double s = 0.0;
        #pragma unroll 4
        for (int q = 0; q < 64; ++q) {
          const float4 ev = Er[q];
          s += (double)ev.x * xsT[q * 4 + 0][r] + (double)ev.y * xsT[q * 4 + 1][r]
             + (double)ev.z * xsT[q * 4 + 2][r] + (double)ev.w * xsT[q * 4 + 3][r];
        }
        const double dd = enorm_d[c] - 2.0 * s;
        if (dd < bd) { bd = dd; bi_ = c; }  // c ascending per thread
      }
      rv[tid] = bd;
      ri[tid] = bi_;
      __syncthreads();
      for (int off = 128; off > 0; off >>= 1) {
        if (tid < off) {
          const double ov = rv[tid + off];
          const int oi = ri[tid + off];
          if (ov < rv[tid] || (ov == rv[tid] && oi < ri[tid])) {
            rv[tid] = ov;
            ri[tid] = oi;
          }
        }
        __syncthreads();
      }
      if (tid == 0) newsh[r] = ri[0];
      __syncthreads();
    }
  }

  // write-back changed rows + exact fp64 loss delta (direct recompute)
  for (int r = 0; r < nr; ++r) {
    const int newi = newsh[r];
    const int oldi = oldsh[r];
    if (newi != oldi) {
      const int row = rowsh[r];
      const float ev = E[(size_t)newi * DK + tid];
      const float eo = E[(size_t)oldi * DK + tid];
      const float x = xsT[tid][r];
      out[(size_t)row * DK + tid] = ev;
      const double dn = (double)ev - (double)x;
      const double dl = (double)eo - (double)x;
      rv[tid] = dn * dn - dl * dl;
      __syncthreads();
      for (int off = 128; off > 0; off >>= 1) {
        if (tid < off) rv[tid] += rv[tid + off];
        __syncthreads();
      }
      if (tid == 0) {
        out[IDX_OFF + row] = (float)newi;
        atomicAdd(&loss_part[row & 63], rv[0]);
      }
      __syncthreads();
    }
  }
}

__global__ __launch_bounds__(64) void finalize(
    const double* __restrict__ loss_part, float* __restrict__ out) {
  double v = loss_part[threadIdx.x];
  for (int o = 32; o > 0; o >>= 1) v += __shfl_down(v, o, 64);
  if (threadIdx.x == 0) out[LOSS_OFF] = (float)(v / 16777216.0);
}

extern "C" void kernel_launch(void* const* d_in, const int* in_sizes, int n_in,
                              void* d_out, int out_size, void* d_ws, size_t ws_size,
                              hipStream_t stream) {
  const float* X = (const float*)d_in[0];  // [65536, 256]
  const float* E = (const float*)d_in[1];  // [1024, 256]
  float* out = (float*)d_out;
  char* ws = (char*)d_ws;

  int*    flag1     = (int*)(ws + WS_FLAG1);
  double* loss_part = (double*)(ws + WS_LOSSP);
  double* enorm_d   = (double*)(ws + WS_ENORMD);
  float*  enorm_f   = (float*)(ws + WS_ENORMF);
  int*    flag_rows = (int*)(ws + WS_FROWS);
  int*    idx_ws    = (int*)(ws + WS_IDX);
  uint4*  Ehi       = (uint4*)(ws + WS_EHI);
  float*  Et        = (float*)(ws + WS_ET);

  hipLaunchKernelGGL(init_kernel, dim3(128), dim3(256), 0, stream,
                     E, enorm_d, enorm_f, Ehi, flag1, loss_part);
  hipLaunchKernelGGL(dist_fused, dim3(NROWS / 64), dim3(256), 0, stream,
                     X, Ehi, E, enorm_f, idx_ws, flag1, flag_rows, out, loss_part);
  // Et overlays Ehi (dead after dist_fused)
  hipLaunchKernelGGL(transposeE, dim3(16), dim3(256), 0, stream, E, Et);
  hipLaunchKernelGGL(fixup_scan, dim3(FLAG_CAP / 4), dim3(256), 0, stream,
                     X, E, Et, enorm_d, enorm_f, flag1, flag_rows, idx_ws, out, loss_part);
  hipLaunchKernelGGL(finalize, dim3(1), dim3(64), 0, stream, loss_part, out);
}

// Round 4
// 219.378 us; speedup vs baseline: 1.3286x; 1.0358x over previous
//
#include <hip/hip_runtime.h>
#include <float.h>

#define NROWS 65536
#define DK 256
#define NCODES 1024
#define FLAG_CAP 8192
#define MARGIN1 0.15f   // f16 single-pass: sigma_d ~0.0065 -> 23 sigma + granule 0.0156
#define D_BIAS 384.0f   // d = enorm + 384 - 2acc in (394, 894): 8-bit pack granule <= 2^-6
#define TIE_EPS 2.0e-3f // fp32 rescan: sigma ~4e-5 -> 50 sigma; ties -> exact fp64 path

#define LOSS_OFF 16777216
#define IDX_OFF  16777217

// LDS fragment chunk stride (dist_fused): 64 fragments x 16 B = 1024 B payload,
// padded to 1040 B so stage-A wave-wide ds_write_b64 rotates 4 banks per chunk.
#define CHUNK_STRIDE 1040

// ---------------- ws layout (bytes) ----------------
#define WS_FLAG1   0        // int
#define WS_LOSSP   8        // double[64]
#define WS_ENORMD  520      // double[1024] -> ends 8712
#define WS_ENORMF  8720     // float[1024]  -> ends 12816 (16B aligned)
#define WS_FROWS   12816    // int[FLAG_CAP] -> ends 45584
#define WS_IDX     45584    // int[65536]    -> ends 307728
#define WS_EHI     307728   // fp16[1024*256] frag-swizzled (512 KB), dead after dist_fused
#define WS_ET      307728   // float[256][1024] E-transposed (1 MB) OVERLAYS Ehi

typedef _Float16 f16x8 __attribute__((ext_vector_type(8)));
typedef float f32x4 __attribute__((ext_vector_type(4)));
typedef unsigned int uint32;

__device__ __forceinline__ uint32 packh2(float a, float b) {
  return (uint32)__builtin_bit_cast(unsigned short, (_Float16)a) |
         ((uint32)__builtin_bit_cast(unsigned short, (_Float16)b) << 16);
}

// ---- init: counters, fp64 E norms, E -> f16 fragment-swizzled Ehi ----
__global__ __launch_bounds__(256) void init_kernel(
    const float* __restrict__ E, double* __restrict__ enorm_d,
    float* __restrict__ enorm_f, uint4* __restrict__ Ehi,
    int* __restrict__ flag1, double* __restrict__ loss_part) {
  const int t = threadIdx.x;
  const int c = blockIdx.x * 8 + (t >> 5);
  const int g = t & 31;  // 8-element group within the code row
  if (blockIdx.x == 0) {
    if (t == 0) *flag1 = 0;
    if (t < 64) loss_part[t] = 0.0;
  }
  const float4* er4 = (const float4*)(E + (size_t)c * DK);
  const float4 va = er4[g * 2];
  const float4 vb = er4[g * 2 + 1];
  double s = (double)va.x * va.x + (double)va.y * va.y + (double)va.z * va.z + (double)va.w * va.w
           + (double)vb.x * vb.x + (double)vb.y * vb.y + (double)vb.z * vb.z + (double)vb.w * vb.w;
  uint4 h;
  h.x = packh2(va.x, va.y);
  h.y = packh2(va.z, va.w);
  h.z = packh2(vb.x, vb.y);
  h.w = packh2(vb.z, vb.w);
  const int ctg = c >> 8, cga = (c >> 4) & 15, col = c & 15;
  const int kc = g >> 2, quad = g & 3;
  Ehi[((size_t)((ctg * 8 + kc) * 16 + cga)) * 64 + (size_t)(quad * 16 + col)] = h;
  #pragma unroll
  for (int m = 1; m < 32; m <<= 1) s += __shfl_xor(s, m, 64);
  if (g == 0) {
    enorm_d[c] = s;
    enorm_f[c] = (float)s;
  }
}

// ---- phase 1 (fused): f16 MFMA distances + top-2 argmin + gather/loss tail ----
__global__ __launch_bounds__(256, 4) void dist_fused(
    const float* __restrict__ X, const uint4* __restrict__ Ehi,
    const float* __restrict__ E, const float* __restrict__ enorm_f,
    int* __restrict__ idx_ws, int* __restrict__ flag1, int* __restrict__ flag_rows,
    float* __restrict__ out, double* __restrict__ loss_part) {
  __shared__ __attribute__((aligned(16))) char lds[33280];
  const int tid = threadIdx.x;
  const int lane = tid & 63;
  const int wid = tid >> 6;
  const int col = lane & 15;
  const int rowBase = blockIdx.x * 64;

  // stage A: 64 rows x 256 k, fp32 -> fp16 RNE, fragment order (rotated chunks)
  {
    const float4* X4 = (const float4*)X + (size_t)rowBase * 64;
    #pragma unroll
    for (int i = 0; i < 16; ++i) {
      const int f4 = i * 256 + tid;
      const int row = f4 >> 6;
      const int k0 = (f4 & 63) << 2;
      const float4 v = X4[f4];
      uint2 p;
      p.x = packh2(v.x, v.y);
      p.y = packh2(v.z, v.w);
      const int chunk = (row >> 4) * 8 + (k0 >> 5);
      const int off = chunk * CHUNK_STRIDE
                      + (((k0 >> 3) & 3) * 16 + (row & 15)) * 16
                      + ((k0 >> 2) & 1) * 8;
      *(uint2*)(lds + off) = p;
    }
  }
  __syncthreads();

  float rv1[16], rv2[16];  // packed top-2 per row; wave-local idx in low 8 bits
  #pragma unroll
  for (int i = 0; i < 16; ++i) { rv1[i] = FLT_MAX; rv2[i] = FLT_MAX; }

  for (int ctg = 0; ctg < 4; ++ctg) {
    f32x4 acc[4][4];
    #pragma unroll
    for (int rg = 0; rg < 4; ++rg)
      #pragma unroll
      for (int cg = 0; cg < 4; ++cg) acc[rg][cg] = (f32x4){0.f, 0.f, 0.f, 0.f};

    #pragma unroll 2
    for (int ks = 0; ks < 8; ++ks) {
      const size_t ub = ((size_t)((ctg * 8 + ks) * 16 + wid * 4)) * 64 + (size_t)lane;
      f16x8 a[4], bh[4];
      #pragma unroll
      for (int cg = 0; cg < 4; ++cg) bh[cg] = *(const f16x8*)&Ehi[ub + (size_t)cg * 64];
      #pragma unroll
      for (int rg = 0; rg < 4; ++rg)
        a[rg] = *(const f16x8*)(lds + (rg * 8 + ks) * CHUNK_STRIDE + lane * 16);
      #pragma unroll
      for (int rg = 0; rg < 4; ++rg)
        #pragma unroll
        for (int cg = 0; cg < 4; ++cg)
          acc[rg][cg] = __builtin_amdgcn_mfma_f32_16x16x32_f16(a[rg], bh[cg], acc[rg][cg], 0, 0, 0);
    }
    // epilogue: d = ||e||^2 + BIAS - 2 acc; pack wave-local idx (8 bits)
    #pragma unroll
    for (int cg = 0; cg < 4; ++cg) {
      const int code = ctg * 256 + wid * 64 + cg * 16 + col;
      const float en = enorm_f[code] + D_BIAS;
      const uint32 li = (uint32)((ctg << 6) | (cg << 4) | col);
      #pragma unroll
      for (int rg = 0; rg < 4; ++rg)
        #pragma unroll
        for (int reg = 0; reg < 4; ++reg) {
          const int i = rg * 4 + reg;
          const float d = fmaf(-2.0f, acc[rg][cg][reg], en);
          const float p = __builtin_bit_cast(float,
              (__builtin_bit_cast(uint32, d) & 0xFFFFFF00u) | li);
          rv2[i] = fminf(rv2[i], fmaxf(rv1[i], p));
          rv1[i] = fminf(rv1[i], p);
        }
    }
  }

  // merge 16 cols within each quad (packed => lowest local idx wins ties)
  #pragma unroll
  for (int i = 0; i < 16; ++i) {
    #pragma unroll
    for (int m = 1; m < 16; m <<= 1) {
      const float o1 = __shfl_xor(rv1[i], m, 64);
      const float o2 = __shfl_xor(rv2[i], m, 64);
      rv2[i] = fminf(fminf(rv2[i], o2), fmaxf(rv1[i], o1));
      rv1[i] = fminf(rv1[i], o1);
    }
  }

  __syncthreads();  // all waves done reading A region
  float* M = (float*)lds;          // [row 64][wave 4][2]  (2 KB)
  int* idxs = (int*)(lds + 4096);  // [64]
  if (col == 0) {
    const int quad = lane >> 4;
    #pragma unroll
    for (int i = 0; i < 16; ++i) {
      const int row = (i >> 2) * 16 + quad * 4 + (i & 3);
      M[(row * 4 + wid) * 2 + 0] = rv1[i];
      M[(row * 4 + wid) * 2 + 1] = rv2[i];
    }
  }
  __syncthreads();
  if (tid < 64) {
    const float a1 = M[(tid * 4 + 0) * 2], a2 = M[(tid * 4 + 0) * 2 + 1];
    const float b1 = M[(tid * 4 + 1) * 2], b2 = M[(tid * 4 + 1) * 2 + 1];
    const float c1 = M[(tid * 4 + 2) * 2], c2 = M[(tid * 4 + 2) * 2 + 1];
    const float d1 = M[(tid * 4 + 3) * 2], d2 = M[(tid * 4 + 3) * 2 + 1];
    const float lo1 = fminf(a1, b1), hi1 = fmaxf(a1, b1);
    const float lo2 = fminf(c1, d1), hi2 = fmaxf(c1, d1);
    const float r1 = fminf(lo1, lo2);
    const float s1 = fminf(fmaxf(lo1, lo2), fminf(hi1, hi2));
    const float r2 = fminf(fminf(fminf(a2, b2), fminf(c2, d2)), s1);
    const int w1 = (r1 == a1) ? 0 : (r1 == b1) ? 1 : (r1 == c1) ? 2 : 3;
    const uint32 u1 = __builtin_bit_cast(uint32, r1);
    const int li = (int)(u1 & 255u);
    const int code = ((li >> 6) & 3) * 256 + w1 * 64 + ((li >> 4) & 3) * 16 + (li & 15);
    const int row = rowBase + tid;
    idxs[tid] = code;
    idx_ws[row] = code;
    out[IDX_OFF + row] = (float)code;
    const float q1 = __builtin_bit_cast(float, u1 & 0xFFFFFF00u);
    const float q2 = __builtin_bit_cast(float, __builtin_bit_cast(uint32, r2) & 0xFFFFFF00u);
    if (q2 - q1 < MARGIN1) {
      const int p = atomicAdd(flag1, 1);
      if (p < FLAG_CAP) flag_rows[p] = row;
    }
  }
  __syncthreads();

  // fused tail: gather quantized, write, fp64 loss partial (provisional idx;
  // fixup rewrites flagged rows and adjusts the loss by the exact delta)
  const int rsub = tid >> 6, c4 = tid & 63;
  double ls = 0.0;
  #pragma unroll 4
  for (int i = 0; i < 16; ++i) {
    const int rl = i * 4 + rsub;
    const int row = rowBase + rl;
    const int idx = idxs[rl];
    const float4 q = ((const float4*)E)[(size_t)idx * 64 + c4];
    const float4 x = ((const float4*)X)[(size_t)row * 64 + c4];
    ((float4*)out)[(size_t)row * 64 + c4] = q;
    const double d0 = (double)q.x - (double)x.x;
    const double d1 = (double)q.y - (double)x.y;
    const double d2 = (double)q.z - (double)x.z;
    const double d3 = (double)q.w - (double)x.w;
    ls += d0 * d0 + d1 * d1 + d2 * d2 + d3 * d3;
  }
  #pragma unroll
  for (int o = 32; o > 0; o >>= 1) ls += __shfl_down(ls, o, 64);
  __shared__ double wsum[4];
  if ((tid & 63) == 0) wsum[tid >> 6] = ls;
  __syncthreads();
  if (tid == 0)
    atomicAdd(&loss_part[blockIdx.x & 63], wsum[0] + wsum[1] + wsum[2] + wsum[3]);
}

// ---- E transpose: Et[k][c] = E[c][k], 1 MB, runs after dist_fused ----
__global__ __launch_bounds__(256) void transposeE(
    const float* __restrict__ E, float* __restrict__ Et) {
  const int t = threadIdx.x;
  const int c = blockIdx.x * 64 + (t & 63);
  const int kq = t >> 6;  // 0..3
  const float4* E4 = (const float4*)(E + (size_t)c * DK) + kq * 16;
  #pragma unroll
  for (int q = 0; q < 16; ++q) {
    const float4 v = E4[q];
    const int k = kq * 64 + q * 4;
    Et[(size_t)k * NCODES + c] = v.x;
    Et[(size_t)(k + 1) * NCODES + c] = v.y;
    Et[(size_t)(k + 2) * NCODES + c] = v.z;
    Et[(size_t)(k + 3) * NCODES + c] = v.w;
  }
}

// ---- phase 2: re-resolution of flagged rows (4 rows/block) ----
// cnt ~ a few hundred rows => ~70 blocks, each on its own CU for the whole
// dispatch: per-BLOCK critical path is the metric, TLP unavailable.
// R3 lesson: VGPR_Count=52 (no launch-bounds hint) => compiler scheduled the
// scan load->wait->use, 800 cyc/iter (full L3 latency, zero MLP). Fix:
// launch_bounds(256,1) releases the register file (1 wave/SIMD anyway) and a
// 16-deep software pipeline keeps 16 global + 16 LDS loads in flight.
__global__ __launch_bounds__(256, 1) void fixup_scan(
    const float* __restrict__ X, const float* __restrict__ E,
    const float* __restrict__ Et, const double* __restrict__ enorm_d,
    const float* __restrict__ enorm_f, const int* __restrict__ flag1,
    const int* __restrict__ flag_rows, const int* __restrict__ idx_ws,
    float* __restrict__ out, double* __restrict__ loss_part) {
  __shared__ __attribute__((aligned(16))) float xsT[256][4];  // [k][row], 4 KB
  __shared__ double rv[256];
  __shared__ int ri[256];
  __shared__ float wv1[4][4], wv2[4][4];
  __shared__ int wi1[4][4];
  __shared__ float fin1[4], fin2[4];
  __shared__ int rowsh[4], oldsh[4], newsh[4];

  int cnt = *flag1;
  if (cnt > FLAG_CAP) cnt = FLAG_CAP;
  const int fbase = blockIdx.x * 4;
  if (fbase >= cnt) return;
  const int nr = min(4, cnt - fbase);
  const int tid = threadIdx.x;
  if (tid < 4) {
    const int row = (tid < nr) ? flag_rows[fbase + tid] : flag_rows[fbase];
    rowsh[tid] = row;
    oldsh[tid] = idx_ws[row];
  }
  __syncthreads();
  #pragma unroll
  for (int r = 0; r < 4; ++r)
    xsT[tid][r] = X[(size_t)rowsh[r] * DK + tid];
  __syncthreads();

  // main scan: 16-chunk software pipeline. Chunk j's Et load (1 KB/wave,
  // coalesced) and x broadcast (ds_read_b128) issued one full 16-iter block
  // ahead of use => 16 loads in flight, ~latency/16 per iter instead of
  // latency per iter. Registers: eb 64 + xb 64 + acc 16 ~ 170 VGPR (ok at 1
  // wave/SIMD). All indices compile-time (arrays stay in registers).
  const f32x4* Et4 = (const f32x4*)Et;
  const f32x4* xv = (const f32x4*)xsT;
  f32x4 acc[4];
  #pragma unroll
  for (int r = 0; r < 4; ++r) acc[r] = (f32x4){0.f, 0.f, 0.f, 0.f};
  f32x4 eb[16], xb[16];
  #pragma unroll
  for (int j = 0; j < 16; ++j) {
    eb[j] = Et4[(size_t)j * 256 + tid];
    xb[j] = xv[j];
  }
  for (int kb = 1; kb < 16; ++kb) {
    #pragma unroll
    for (int j = 0; j < 16; ++j) {
      const f32x4 e = eb[j];
      const f32x4 xk = xb[j];
      const int kn = kb * 16 + j;
      eb[j] = Et4[(size_t)kn * 256 + tid];
      xb[j] = xv[kn];
      acc[0] += e * xk[0];
      acc[1] += e * xk[1];
      acc[2] += e * xk[2];
      acc[3] += e * xk[3];
    }
  }
  #pragma unroll
  for (int j = 0; j < 16; ++j) {
    const f32x4 e = eb[j];
    const f32x4 xk = xb[j];
    acc[0] += e * xk[0];
    acc[1] += e * xk[1];
    acc[2] += e * xk[2];
    acc[3] += e * xk[3];
  }

  // per-thread top-2 over its 4 codes (j ascending -> lowest idx wins ties)
  float v1[4], v2[4];
  int i1[4];
  #pragma unroll
  for (int r = 0; r < 4; ++r) { v1[r] = FLT_MAX; v2[r] = FLT_MAX; i1[r] = 0; }
  const float4 en4 = ((const float4*)enorm_f)[tid];
  const float en[4] = {en4.x, en4.y, en4.z, en4.w};
  #pragma unroll
  for (int j = 0; j < 4; ++j) {
    const int code = tid * 4 + j;
    #pragma unroll
    for (int r = 0; r < 4; ++r) {
      const float d = fmaf(-2.0f, acc[r][j], en[j]);
      if (d < v1[r]) { v2[r] = v1[r]; v1[r] = d; i1[r] = code; }
      else v2[r] = fminf(v2[r], d);
    }
  }

  // wave-level top-2 butterfly, then 4-wave merge
  const int lane = tid & 63, wid = tid >> 6;
  #pragma unroll
  for (int r = 0; r < 4; ++r) {
    float b1 = v1[r], b2 = v2[r];
    int bi = i1[r];
    #pragma unroll
    for (int m = 1; m < 64; m <<= 1) {
      const float o1 = __shfl_xor(b1, m, 64);
      const float o2 = __shfl_xor(b2, m, 64);
      const int oi = __shfl_xor(bi, m, 64);
      const float hi = fmaxf(b1, o1);
      b2 = fminf(fminf(b2, o2), hi);
      if (o1 < b1 || (o1 == b1 && oi < bi)) { b1 = o1; bi = oi; }
    }
    if (lane == 0) { wv1[wid][r] = b1; wi1[wid][r] = bi; wv2[wid][r] = b2; }
  }
  __syncthreads();
  if (tid < 4) {  // tid = row
    float b1 = wv1[0][tid], b2 = wv2[0][tid];
    int bi = wi1[0][tid];
    #pragma unroll
    for (int w = 1; w < 4; ++w) {
      const float o1 = wv1[w][tid], o2 = wv2[w][tid];
      const int oi = wi1[w][tid];
      b2 = fminf(fminf(b2, o2), fmaxf(b1, o1));
      if (o1 < b1 || (o1 == b1 && oi < bi)) { b1 = o1; bi = oi; }
    }
    fin1[tid] = b1;
    fin2[tid] = b2;
    newsh[tid] = bi;
  }
  __syncthreads();

  // rare exact-fp64 tie resolution (block-uniform branch per row)
  for (int r = 0; r < nr; ++r) {
    if (fin2[r] - fin1[r] < TIE_EPS) {
      double bd = 1e300;
      int bi_ = 0x7fffffff;
      for (int cc = 0; cc < 4; ++cc) {
        const int c = cc * 256 + tid;
        const float4* Er = (const float4*)(E + (size_t)c * DK);
        double s = 0.0;
        #pragma unroll 4
        for (int q = 0; q < 64; ++q) {
          const float4 ev = Er[q];
          s += (double)ev.x * xsT[q * 4 + 0][r] + (double)ev.y * xsT[q * 4 + 1][r]
             + (double)ev.z * xsT[q * 4 + 2][r] + (double)ev.w * xsT[q * 4 + 3][r];
        }
        const double dd = enorm_d[c] - 2.0 * s;
        if (dd < bd) { bd = dd; bi_ = c; }  // c ascending per thread
      }
      rv[tid] = bd;
      ri[tid] = bi_;
      __syncthreads();
      for (int off = 128; off > 0; off >>= 1) {
        if (tid < off) {
          const double ov = rv[tid + off];
          const int oi = ri[tid + off];
          if (ov < rv[tid] || (ov == rv[tid] && oi < ri[tid])) {
            rv[tid] = ov;
            ri[tid] = oi;
          }
        }
        __syncthreads();
      }
      if (tid == 0) newsh[r] = ri[0];
      __syncthreads();
    }
  }

  // write-back changed rows + exact fp64 loss delta (direct recompute)
  for (int r = 0; r < nr; ++r) {
    const int newi = newsh[r];
    const int oldi = oldsh[r];
    if (newi != oldi) {
      const int row = rowsh[r];
      const float ev = E[(size_t)newi * DK + tid];
      const float eo = E[(size_t)oldi * DK + tid];
      const float x = xsT[tid][r];
      out[(size_t)row * DK + tid] = ev;
      const double dn = (double)ev - (double)x;
      const double dl = (double)eo - (double)x;
      rv[tid] = dn * dn - dl * dl;
      __syncthreads();
      for (int off = 128; off > 0; off >>= 1) {
        if (tid < off) rv[tid] += rv[tid + off];
        __syncthreads();
      }
      if (tid == 0) {
        out[IDX_OFF + row] = (float)newi;
        atomicAdd(&loss_part[row & 63], rv[0]);
      }
      __syncthreads();
    }
  }
}

__global__ __launch_bounds__(64) void finalize(
    const double* __restrict__ loss_part, float* __restrict__ out) {
  double v = loss_part[threadIdx.x];
  for (int o = 32; o > 0; o >>= 1) v += __shfl_down(v, o, 64);
  if (threadIdx.x == 0) out[LOSS_OFF] = (float)(v / 16777216.0);
}

extern "C" void kernel_launch(void* const* d_in, const int* in_sizes, int n_in,
                              void* d_out, int out_size, void* d_ws, size_t ws_size,
                              hipStream_t stream) {
  const float* X = (const float*)d_in[0];  // [65536, 256]
  const float* E = (const float*)d_in[1];  // [1024, 256]
  float* out = (float*)d_out;
  char* ws = (char*)d_ws;

  int*    flag1     = (int*)(ws + WS_FLAG1);
  double* loss_part = (double*)(ws + WS_LOSSP);
  double* enorm_d   = (double*)(ws + WS_ENORMD);
  float*  enorm_f   = (float*)(ws + WS_ENORMF);
  int*    flag_rows = (int*)(ws + WS_FROWS);
  int*    idx_ws    = (int*)(ws + WS_IDX);
  uint4*  Ehi       = (uint4*)(ws + WS_EHI);
  float*  Et        = (float*)(ws + WS_ET);

  hipLaunchKernelGGL(init_kernel, dim3(128), dim3(256), 0, stream,
                     E, enorm_d, enorm_f, Ehi, flag1, loss_part);
  hipLaunchKernelGGL(dist_fused, dim3(NROWS / 64), dim3(256), 0, stream,
                     X, Ehi, E, enorm_f, idx_ws, flag1, flag_rows, out, loss_part);
  // Et overlays Ehi (dead after dist_fused)
  hipLaunchKernelGGL(transposeE, dim3(16), dim3(256), 0, stream, E, Et);
  hipLaunchKernelGGL(fixup_scan, dim3(FLAG_CAP / 4), dim3(256), 0, stream,
                     X, E, Et, enorm_d, enorm_f, flag1, flag_rows, idx_ws, out, loss_part);
  hipLaunchKernelGGL(finalize, dim3(1), dim3(64), 0, stream, loss_part, out);
}

// Round 5
// 196.238 us; speedup vs baseline: 1.4852x; 1.1179x over previous
//
#include <hip/hip_runtime.h>
#include <float.h>

#define NROWS 65536
#define DK 256
#define NCODES 1024
#define FLAG_CAP 8192
#define MARGIN1 0.15f   // f16 single-pass: sigma_d ~0.0065 -> 23 sigma + granule 0.0156
#define D_BIAS 384.0f   // d = enorm + 384 - 2acc in (394, 894): 8-bit pack granule <= 2^-6
#define TIE_EPS 2.0e-3f // fp32 rescan: sigma ~4e-5 -> 50 sigma; ties -> exact fp64 path

#define LOSS_OFF 16777216
#define IDX_OFF  16777217

// LDS fragment chunk stride (dist_fused): 64 fragments x 16 B = 1024 B payload,
// padded to 1040 B so stage-A wave-wide ds_write_b64 rotates 4 banks per chunk.
#define CHUNK_STRIDE 1040

// ---------------- ws layout (bytes) ----------------
#define WS_FLAG1   0        // int
#define WS_LOSSP   8        // double[64]
#define WS_ENORMD  520      // double[1024] -> ends 8712
#define WS_ENORMF  8720     // float[1024]  -> ends 12816 (16B aligned)
#define WS_FROWS   12816    // int[FLAG_CAP] -> ends 45584
#define WS_IDX     45584    // int[65536]    -> ends 307728
#define WS_EHI     307728   // fp16[1024*256] frag-swizzled (512 KB), dead after dist_fused
#define WS_ET      307728   // float[256][1024] E-transposed (1 MB) OVERLAYS Ehi

typedef _Float16 f16x8 __attribute__((ext_vector_type(8)));
typedef float f32x4 __attribute__((ext_vector_type(4)));
typedef unsigned int uint32;

__device__ __forceinline__ uint32 packh2(float a, float b) {
  return (uint32)__builtin_bit_cast(unsigned short, (_Float16)a) |
         ((uint32)__builtin_bit_cast(unsigned short, (_Float16)b) << 16);
}

// ---- init: counters, fp64 E norms, E -> f16 fragment-swizzled Ehi ----
__global__ __launch_bounds__(256) void init_kernel(
    const float* __restrict__ E, double* __restrict__ enorm_d,
    float* __restrict__ enorm_f, uint4* __restrict__ Ehi,
    int* __restrict__ flag1, double* __restrict__ loss_part) {
  const int t = threadIdx.x;
  const int c = blockIdx.x * 8 + (t >> 5);
  const int g = t & 31;  // 8-element group within the code row
  if (blockIdx.x == 0) {
    if (t == 0) *flag1 = 0;
    if (t < 64) loss_part[t] = 0.0;
  }
  const float4* er4 = (const float4*)(E + (size_t)c * DK);
  const float4 va = er4[g * 2];
  const float4 vb = er4[g * 2 + 1];
  double s = (double)va.x * va.x + (double)va.y * va.y + (double)va.z * va.z + (double)va.w * va.w
           + (double)vb.x * vb.x + (double)vb.y * vb.y + (double)vb.z * vb.z + (double)vb.w * vb.w;
  uint4 h;
  h.x = packh2(va.x, va.y);
  h.y = packh2(va.z, va.w);
  h.z = packh2(vb.x, vb.y);
  h.w = packh2(vb.z, vb.w);
  const int ctg = c >> 8, cga = (c >> 4) & 15, col = c & 15;
  const int kc = g >> 2, quad = g & 3;
  Ehi[((size_t)((ctg * 8 + kc) * 16 + cga)) * 64 + (size_t)(quad * 16 + col)] = h;
  #pragma unroll
  for (int m = 1; m < 32; m <<= 1) s += __shfl_xor(s, m, 64);
  if (g == 0) {
    enorm_d[c] = s;
    enorm_f[c] = (float)s;
  }
}

// ---- phase 1 (fused): f16 MFMA distances + top-2 argmin + gather/loss tail ----
__global__ __launch_bounds__(256, 4) void dist_fused(
    const float* __restrict__ X, const uint4* __restrict__ Ehi,
    const float* __restrict__ E, const float* __restrict__ enorm_f,
    int* __restrict__ idx_ws, int* __restrict__ flag1, int* __restrict__ flag_rows,
    float* __restrict__ out, double* __restrict__ loss_part) {
  __shared__ __attribute__((aligned(16))) char lds[33280];
  const int tid = threadIdx.x;
  const int lane = tid & 63;
  const int wid = tid >> 6;
  const int col = lane & 15;
  const int rowBase = blockIdx.x * 64;

  // stage A: 64 rows x 256 k, fp32 -> fp16 RNE, fragment order (rotated chunks)
  {
    const float4* X4 = (const float4*)X + (size_t)rowBase * 64;
    #pragma unroll
    for (int i = 0; i < 16; ++i) {
      const int f4 = i * 256 + tid;
      const int row = f4 >> 6;
      const int k0 = (f4 & 63) << 2;
      const float4 v = X4[f4];
      uint2 p;
      p.x = packh2(v.x, v.y);
      p.y = packh2(v.z, v.w);
      const int chunk = (row >> 4) * 8 + (k0 >> 5);
      const int off = chunk * CHUNK_STRIDE
                      + (((k0 >> 3) & 3) * 16 + (row & 15)) * 16
                      + ((k0 >> 2) & 1) * 8;
      *(uint2*)(lds + off) = p;
    }
  }
  __syncthreads();

  float rv1[16], rv2[16];  // packed top-2 per row; wave-local idx in low 8 bits
  #pragma unroll
  for (int i = 0; i < 16; ++i) { rv1[i] = FLT_MAX; rv2[i] = FLT_MAX; }

  for (int ctg = 0; ctg < 4; ++ctg) {
    f32x4 acc[4][4];
    #pragma unroll
    for (int rg = 0; rg < 4; ++rg)
      #pragma unroll
      for (int cg = 0; cg < 4; ++cg) acc[rg][cg] = (f32x4){0.f, 0.f, 0.f, 0.f};

    #pragma unroll 2
    for (int ks = 0; ks < 8; ++ks) {
      const size_t ub = ((size_t)((ctg * 8 + ks) * 16 + wid * 4)) * 64 + (size_t)lane;
      f16x8 a[4], bh[4];
      #pragma unroll
      for (int cg = 0; cg < 4; ++cg) bh[cg] = *(const f16x8*)&Ehi[ub + (size_t)cg * 64];
      #pragma unroll
      for (int rg = 0; rg < 4; ++rg)
        a[rg] = *(const f16x8*)(lds + (rg * 8 + ks) * CHUNK_STRIDE + lane * 16);
      #pragma unroll
      for (int rg = 0; rg < 4; ++rg)
        #pragma unroll
        for (int cg = 0; cg < 4; ++cg)
          acc[rg][cg] = __builtin_amdgcn_mfma_f32_16x16x32_f16(a[rg], bh[cg], acc[rg][cg], 0, 0, 0);
    }
    // epilogue: d = ||e||^2 + BIAS - 2 acc; pack wave-local idx (8 bits)
    #pragma unroll
    for (int cg = 0; cg < 4; ++cg) {
      const int code = ctg * 256 + wid * 64 + cg * 16 + col;
      const float en = enorm_f[code] + D_BIAS;
      const uint32 li = (uint32)((ctg << 6) | (cg << 4) | col);
      #pragma unroll
      for (int rg = 0; rg < 4; ++rg)
        #pragma unroll
        for (int reg = 0; reg < 4; ++reg) {
          const int i = rg * 4 + reg;
          const float d = fmaf(-2.0f, acc[rg][cg][reg], en);
          const float p = __builtin_bit_cast(float,
              (__builtin_bit_cast(uint32, d) & 0xFFFFFF00u) | li);
          rv2[i] = fminf(rv2[i], fmaxf(rv1[i], p));
          rv1[i] = fminf(rv1[i], p);
        }
    }
  }

  // merge 16 cols within each quad (packed => lowest local idx wins ties)
  #pragma unroll
  for (int i = 0; i < 16; ++i) {
    #pragma unroll
    for (int m = 1; m < 16; m <<= 1) {
      const float o1 = __shfl_xor(rv1[i], m, 64);
      const float o2 = __shfl_xor(rv2[i], m, 64);
      rv2[i] = fminf(fminf(rv2[i], o2), fmaxf(rv1[i], o1));
      rv1[i] = fminf(rv1[i], o1);
    }
  }

  __syncthreads();  // all waves done reading A region
  float* M = (float*)lds;          // [row 64][wave 4][2]  (2 KB)
  int* idxs = (int*)(lds + 4096);  // [64]
  if (col == 0) {
    const int quad = lane >> 4;
    #pragma unroll
    for (int i = 0; i < 16; ++i) {
      const int row = (i >> 2) * 16 + quad * 4 + (i & 3);
      M[(row * 4 + wid) * 2 + 0] = rv1[i];
      M[(row * 4 + wid) * 2 + 1] = rv2[i];
    }
  }
  __syncthreads();
  if (tid < 64) {
    const float a1 = M[(tid * 4 + 0) * 2], a2 = M[(tid * 4 + 0) * 2 + 1];
    const float b1 = M[(tid * 4 + 1) * 2], b2 = M[(tid * 4 + 1) * 2 + 1];
    const float c1 = M[(tid * 4 + 2) * 2], c2 = M[(tid * 4 + 2) * 2 + 1];
    const float d1 = M[(tid * 4 + 3) * 2], d2 = M[(tid * 4 + 3) * 2 + 1];
    const float lo1 = fminf(a1, b1), hi1 = fmaxf(a1, b1);
    const float lo2 = fminf(c1, d1), hi2 = fmaxf(c1, d1);
    const float r1 = fminf(lo1, lo2);
    const float s1 = fminf(fmaxf(lo1, lo2), fminf(hi1, hi2));
    const float r2 = fminf(fminf(fminf(a2, b2), fminf(c2, d2)), s1);
    const int w1 = (r1 == a1) ? 0 : (r1 == b1) ? 1 : (r1 == c1) ? 2 : 3;
    const uint32 u1 = __builtin_bit_cast(uint32, r1);
    const int li = (int)(u1 & 255u);
    const int code = ((li >> 6) & 3) * 256 + w1 * 64 + ((li >> 4) & 3) * 16 + (li & 15);
    const int row = rowBase + tid;
    idxs[tid] = code;
    idx_ws[row] = code;
    out[IDX_OFF + row] = (float)code;
    const float q1 = __builtin_bit_cast(float, u1 & 0xFFFFFF00u);
    const float q2 = __builtin_bit_cast(float, __builtin_bit_cast(uint32, r2) & 0xFFFFFF00u);
    if (q2 - q1 < MARGIN1) {
      const int p = atomicAdd(flag1, 1);
      if (p < FLAG_CAP) flag_rows[p] = row;
    }
  }
  __syncthreads();

  // fused tail: gather quantized, write, fp64 loss partial (provisional idx;
  // fixup rewrites flagged rows and adjusts the loss by the exact delta)
  const int rsub = tid >> 6, c4 = tid & 63;
  double ls = 0.0;
  #pragma unroll 4
  for (int i = 0; i < 16; ++i) {
    const int rl = i * 4 + rsub;
    const int row = rowBase + rl;
    const int idx = idxs[rl];
    const float4 q = ((const float4*)E)[(size_t)idx * 64 + c4];
    const float4 x = ((const float4*)X)[(size_t)row * 64 + c4];
    ((float4*)out)[(size_t)row * 64 + c4] = q;
    const double d0 = (double)q.x - (double)x.x;
    const double d1 = (double)q.y - (double)x.y;
    const double d2 = (double)q.z - (double)x.z;
    const double d3 = (double)q.w - (double)x.w;
    ls += d0 * d0 + d1 * d1 + d2 * d2 + d3 * d3;
  }
  #pragma unroll
  for (int o = 32; o > 0; o >>= 1) ls += __shfl_down(ls, o, 64);
  __shared__ double wsum[4];
  if ((tid & 63) == 0) wsum[tid >> 6] = ls;
  __syncthreads();
  if (tid == 0)
    atomicAdd(&loss_part[blockIdx.x & 63], wsum[0] + wsum[1] + wsum[2] + wsum[3]);
}

// ---- E transpose: Et[k][c] = E[c][k], 1 MB, runs after dist_fused ----
__global__ __launch_bounds__(256) void transposeE(
    const float* __restrict__ E, float* __restrict__ Et) {
  const int t = threadIdx.x;
  const int c = blockIdx.x * 64 + (t & 63);
  const int kq = t >> 6;  // 0..3
  const float4* E4 = (const float4*)(E + (size_t)c * DK) + kq * 16;
  #pragma unroll
  for (int q = 0; q < 16; ++q) {
    const float4 v = E4[q];
    const int k = kq * 64 + q * 4;
    Et[(size_t)k * NCODES + c] = v.x;
    Et[(size_t)(k + 1) * NCODES + c] = v.y;
    Et[(size_t)(k + 2) * NCODES + c] = v.z;
    Et[(size_t)(k + 3) * NCODES + c] = v.w;
  }
}

// ---- phase 2: re-resolution of flagged rows (4 rows/block) ----
// cnt ~ 200 rows => ~50-70 blocks, each on its own CU: per-BLOCK critical
// path is the metric. The fp32 scan is the R4 16-deep pipelined version.
// R5 fix: the fp64 TIE path was still the R1-style divergent row-major scan
// (1 KB-stride per lane, ~77 us latency chain) — it was the hidden floor of
// every fixup variant since R1 (77/85/82 us across 3 different main scans).
// Now the tie path uses the same coalesced Et layout in fp64 (<~3 us/row).
__global__ __launch_bounds__(256, 1) void fixup_scan(
    const float* __restrict__ X, const float* __restrict__ E,
    const float* __restrict__ Et, const double* __restrict__ enorm_d,
    const float* __restrict__ enorm_f, const int* __restrict__ flag1,
    const int* __restrict__ flag_rows, const int* __restrict__ idx_ws,
    float* __restrict__ out, double* __restrict__ loss_part) {
  __shared__ __attribute__((aligned(16))) float xsT[256][4];  // [k][row], 4 KB
  __shared__ double rv[256];
  __shared__ int ri[256];
  __shared__ float wv1[4][4], wv2[4][4];
  __shared__ int wi1[4][4];
  __shared__ float fin1[4], fin2[4];
  __shared__ int rowsh[4], oldsh[4], newsh[4];

  int cnt = *flag1;
  if (cnt > FLAG_CAP) cnt = FLAG_CAP;
  const int fbase = blockIdx.x * 4;
  if (fbase >= cnt) return;
  const int nr = min(4, cnt - fbase);
  const int tid = threadIdx.x;
  if (tid < 4) {
    const int row = (tid < nr) ? flag_rows[fbase + tid] : flag_rows[fbase];
    rowsh[tid] = row;
    oldsh[tid] = idx_ws[row];
  }
  __syncthreads();
  #pragma unroll
  for (int r = 0; r < 4; ++r)
    xsT[tid][r] = X[(size_t)rowsh[r] * DK + tid];
  __syncthreads();

  // main scan: 16-chunk software pipeline (R4). Chunk j's Et load (coalesced)
  // and x broadcast issued one full 16-iter block ahead of use.
  const f32x4* Et4 = (const f32x4*)Et;
  const f32x4* xv = (const f32x4*)xsT;
  f32x4 acc[4];
  #pragma unroll
  for (int r = 0; r < 4; ++r) acc[r] = (f32x4){0.f, 0.f, 0.f, 0.f};
  f32x4 eb[16], xb[16];
  #pragma unroll
  for (int j = 0; j < 16; ++j) {
    eb[j] = Et4[(size_t)j * 256 + tid];
    xb[j] = xv[j];
  }
  for (int kb = 1; kb < 16; ++kb) {
    #pragma unroll
    for (int j = 0; j < 16; ++j) {
      const f32x4 e = eb[j];
      const f32x4 xk = xb[j];
      const int kn = kb * 16 + j;
      eb[j] = Et4[(size_t)kn * 256 + tid];
      xb[j] = xv[kn];
      acc[0] += e * xk[0];
      acc[1] += e * xk[1];
      acc[2] += e * xk[2];
      acc[3] += e * xk[3];
    }
  }
  #pragma unroll
  for (int j = 0; j < 16; ++j) {
    const f32x4 e = eb[j];
    const f32x4 xk = xb[j];
    acc[0] += e * xk[0];
    acc[1] += e * xk[1];
    acc[2] += e * xk[2];
    acc[3] += e * xk[3];
  }

  // per-thread top-2 over its 4 codes (j ascending -> lowest idx wins ties)
  float v1[4], v2[4];
  int i1[4];
  #pragma unroll
  for (int r = 0; r < 4; ++r) { v1[r] = FLT_MAX; v2[r] = FLT_MAX; i1[r] = 0; }
  const float4 en4 = ((const float4*)enorm_f)[tid];
  const float en[4] = {en4.x, en4.y, en4.z, en4.w};
  #pragma unroll
  for (int j = 0; j < 4; ++j) {
    const int code = tid * 4 + j;
    #pragma unroll
    for (int r = 0; r < 4; ++r) {
      const float d = fmaf(-2.0f, acc[r][j], en[j]);
      if (d < v1[r]) { v2[r] = v1[r]; v1[r] = d; i1[r] = code; }
      else v2[r] = fminf(v2[r], d);
    }
  }

  // wave-level top-2 butterfly, then 4-wave merge
  const int lane = tid & 63, wid = tid >> 6;
  #pragma unroll
  for (int r = 0; r < 4; ++r) {
    float b1 = v1[r], b2 = v2[r];
    int bi = i1[r];
    #pragma unroll
    for (int m = 1; m < 64; m <<= 1) {
      const float o1 = __shfl_xor(b1, m, 64);
      const float o2 = __shfl_xor(b2, m, 64);
      const int oi = __shfl_xor(bi, m, 64);
      const float hi = fmaxf(b1, o1);
      b2 = fminf(fminf(b2, o2), hi);
      if (o1 < b1 || (o1 == b1 && oi < bi)) { b1 = o1; bi = oi; }
    }
    if (lane == 0) { wv1[wid][r] = b1; wi1[wid][r] = bi; wv2[wid][r] = b2; }
  }
  __syncthreads();
  if (tid < 4) {  // tid = row
    float b1 = wv1[0][tid], b2 = wv2[0][tid];
    int bi = wi1[0][tid];
    #pragma unroll
    for (int w = 1; w < 4; ++w) {
      const float o1 = wv1[w][tid], o2 = wv2[w][tid];
      const int oi = wi1[w][tid];
      b2 = fminf(fminf(b2, o2), fmaxf(b1, o1));
      if (o1 < b1 || (o1 == b1 && oi < bi)) { b1 = o1; bi = oi; }
    }
    fin1[tid] = b1;
    fin2[tid] = b2;
    newsh[tid] = bi;
  }
  __syncthreads();

  // rare fp64 tie resolution — now COALESCED via Et (same ownership as the
  // fp32 scan: thread owns codes 4t..4t+3). Per k: one contiguous f32x4 load
  // + one LDS broadcast; 4 independent fp64 FMA chains. Block-uniform branch.
  for (int r = 0; r < nr; ++r) {
    if (fin2[r] - fin1[r] < TIE_EPS) {
      double s0 = 0.0, s1 = 0.0, s2 = 0.0, s3 = 0.0;
      #pragma unroll 8
      for (int k = 0; k < 256; ++k) {
        const f32x4 e4 = Et4[(size_t)k * 256 + tid];
        const double xk = (double)xsT[k][r];
        s0 += (double)e4[0] * xk;
        s1 += (double)e4[1] * xk;
        s2 += (double)e4[2] * xk;
        s3 += (double)e4[3] * xk;
      }
      const int c0 = tid * 4;
      double bd = enorm_d[c0] - 2.0 * s0;
      int bi_ = c0;
      const double dd1 = enorm_d[c0 + 1] - 2.0 * s1;
      if (dd1 < bd) { bd = dd1; bi_ = c0 + 1; }
      const double dd2 = enorm_d[c0 + 2] - 2.0 * s2;
      if (dd2 < bd) { bd = dd2; bi_ = c0 + 2; }
      const double dd3 = enorm_d[c0 + 3] - 2.0 * s3;
      if (dd3 < bd) { bd = dd3; bi_ = c0 + 3; }
      rv[tid] = bd;
      ri[tid] = bi_;
      __syncthreads();
      for (int off = 128; off > 0; off >>= 1) {
        if (tid < off) {
          const double ov = rv[tid + off];
          const int oi = ri[tid + off];
          if (ov < rv[tid] || (ov == rv[tid] && oi < ri[tid])) {
            rv[tid] = ov;
            ri[tid] = oi;
          }
        }
        __syncthreads();
      }
      if (tid == 0) newsh[r] = ri[0];
      __syncthreads();
    }
  }

  // write-back changed rows + exact fp64 loss delta (direct recompute)
  for (int r = 0; r < nr; ++r) {
    const int newi = newsh[r];
    const int oldi = oldsh[r];
    if (newi != oldi) {
      const int row = rowsh[r];
      const float ev = E[(size_t)newi * DK + tid];
      const float eo = E[(size_t)oldi * DK + tid];
      const float x = xsT[tid][r];
      out[(size_t)row * DK + tid] = ev;
      const double dn = (double)ev - (double)x;
      const double dl = (double)eo - (double)x;
      rv[tid] = dn * dn - dl * dl;
      __syncthreads();
      for (int off = 128; off > 0; off >>= 1) {
        if (tid < off) rv[tid] += rv[tid + off];
        __syncthreads();
      }
      if (tid == 0) {
        out[IDX_OFF + row] = (float)newi;
        atomicAdd(&loss_part[row & 63], rv[0]);
      }
      __syncthreads();
    }
  }
}

__global__ __launch_bounds__(64) void finalize(
    const double* __restrict__ loss_part, float* __restrict__ out) {
  double v = loss_part[threadIdx.x];
  for (int o = 32; o > 0; o >>= 1) v += __shfl_down(v, o, 64);
  if (threadIdx.x == 0) out[LOSS_OFF] = (float)(v / 16777216.0);
}

extern "C" void kernel_launch(void* const* d_in, const int* in_sizes, int n_in,
                              void* d_out, int out_size, void* d_ws, size_t ws_size,
                              hipStream_t stream) {
  const float* X = (const float*)d_in[0];  // [65536, 256]
  const float* E = (const float*)d_in[1];  // [1024, 256]
  float* out = (float*)d_out;
  char* ws = (char*)d_ws;

  int*    flag1     = (int*)(ws + WS_FLAG1);
  double* loss_part = (double*)(ws + WS_LOSSP);
  double* enorm_d   = (double*)(ws + WS_ENORMD);
  float*  enorm_f   = (float*)(ws + WS_ENORMF);
  int*    flag_rows = (int*)(ws + WS_FROWS);
  int*    idx_ws    = (int*)(ws + WS_IDX);
  uint4*  Ehi       = (uint4*)(ws + WS_EHI);
  float*  Et        = (float*)(ws + WS_ET);

  hipLaunchKernelGGL(init_kernel, dim3(128), dim3(256), 0, stream,
                     E, enorm_d, enorm_f, Ehi, flag1, loss_part);
  hipLaunchKernelGGL(dist_fused, dim3(NROWS / 64), dim3(256), 0, stream,
                     X, Ehi, E, enorm_f, idx_ws, flag1, flag_rows, out, loss_part);
  // Et overlays Ehi (dead after dist_fused)
  hipLaunchKernelGGL(transposeE, dim3(16), dim3(256), 0, stream, E, Et);
  hipLaunchKernelGGL(fixup_scan, dim3(FLAG_CAP / 4), dim3(256), 0, stream,
                     X, E, Et, enorm_d, enorm_f, flag1, flag_rows, idx_ws, out, loss_part);
  hipLaunchKernelGGL(finalize, dim3(1), dim3(64), 0, stream, loss_part, out);
}